// Round 12
// baseline (691.941 us; speedup 1.0000x reference)
//
#include <hip/hip_runtime.h>
#include <cstdint>
#include <cstddef>

typedef unsigned short u16;
typedef unsigned int u32;

using short8 = __attribute__((ext_vector_type(8))) short;
using f32x4  = __attribute__((ext_vector_type(4))) float;

__device__ __forceinline__ float b2f(u16 v) {
  union { u32 u; float f; } c; c.u = ((u32)v) << 16; return c.f;
}
__device__ __forceinline__ u16 f2b(float f) {
  union { float f; u32 u; } c; c.f = f;
  u32 u = c.u;
  u += 0x7fffu + ((u >> 16) & 1u);   // round-to-nearest-even
  return (u16)(u >> 16);
}

// ---------------- fp32 -> bf16 convert ----------------
__global__ __launch_bounds__(256)
void f2bf_kernel(const float* __restrict__ in, u16* __restrict__ outp) {
  int i = blockIdx.x * 256 + threadIdx.x;
  float2 v = *(const float2*)(in + (size_t)i * 2);
  *(u32*)(outp + (size_t)i * 2) = (u32)f2b(v.x) | ((u32)f2b(v.y) << 16);
}

// ---------------- weight prep: W[K,N] fp32 -> Bt[N,K] bf16, stack biases ----------------
__global__ __launch_bounds__(256)
void prep_kernel(const float* __restrict__ Wl1, const float* __restrict__ Wl2,
                 const float* __restrict__ Wq,  const float* __restrict__ Wk,
                 const float* __restrict__ Wv,  const float* __restrict__ Wo,
                 const float* __restrict__ Wf1, const float* __restrict__ Wf2,
                 const float* __restrict__ bl1, const float* __restrict__ bl2,
                 const float* __restrict__ bq,  const float* __restrict__ bk,
                 const float* __restrict__ bv,  const float* __restrict__ bo,
                 const float* __restrict__ bf1, const float* __restrict__ bf2,
                 u16* __restrict__ Bt, float* __restrict__ biasAll) {
  int idx = blockIdx.x * 256 + threadIdx.x;
  if (idx < 196608) {
    const float* W; int local, ks, N;
    if      (idx <  32768) { W = Wl1; local = idx;          ks = 7; N = 256; }
    else if (idx <  65536) { W = Wl2; local = idx - 32768;  ks = 8; N = 128; }
    else if (idx <  81920) { W = Wq;  local = idx - 65536;  ks = 7; N = 128; }
    else if (idx <  98304) { W = Wk;  local = idx - 81920;  ks = 7; N = 128; }
    else if (idx < 114688) { W = Wv;  local = idx - 98304;  ks = 7; N = 128; }
    else if (idx < 131072) { W = Wo;  local = idx - 114688; ks = 7; N = 128; }
    else if (idx < 163840) { W = Wf1; local = idx - 131072; ks = 7; N = 256; }
    else                   { W = Wf2; local = idx - 163840; ks = 8; N = 128; }
    int n = local >> ks, k = local & ((1 << ks) - 1);
    Bt[idx] = f2b(W[(size_t)k * N + n]);
  }
  int t = idx - 196608;
  if (t >= 0 && t < 1280) {
    float v;
    if      (t <  256) v = bl1[t];
    else if (t <  384) v = bl2[t - 256];
    else if (t <  512) v = bq[t - 384];
    else if (t <  640) v = bk[t - 512];
    else if (t <  768) v = bv[t - 640];
    else if (t <  896) v = bo[t - 768];
    else if (t < 1152) v = bf1[t - 896];
    else               v = bf2[t - 1152];
    biasAll[t] = v;
  }
}

// ---------------- CSR build ----------------
__global__ void hist_kernel(const int* __restrict__ dst, int* __restrict__ deg, int E) {
  int i = blockIdx.x * 256 + threadIdx.x;
  if (i < E) atomicAdd(&deg[dst[i]], 1);
}

__global__ __launch_bounds__(256)
void scan1_kernel(const int* __restrict__ deg, int* __restrict__ bsum) {
  int t = threadIdx.x, b = blockIdx.x;
  int v = deg[b * 256 + t];
#pragma unroll
  for (int off = 1; off < 64; off <<= 1) v += __shfl_xor(v, off);
  __shared__ int wsum[4];
  if ((t & 63) == 0) wsum[t >> 6] = v;
  __syncthreads();
  if (t == 0) bsum[b] = wsum[0] + wsum[1] + wsum[2] + wsum[3];
}

__global__ void scan2_kernel(const int* __restrict__ bsum, int* __restrict__ boff,
                             int* __restrict__ rowptrN) {
  __shared__ int sh[128];
  int t = threadIdx.x;
  int v = bsum[t];
  sh[t] = v;
  __syncthreads();
  for (int off = 1; off < 128; off <<= 1) {
    int u = (t >= off) ? sh[t - off] : 0;
    __syncthreads();
    sh[t] += u;
    __syncthreads();
  }
  boff[t] = sh[t] - v;
  if (t == 127) *rowptrN = sh[127];
}

__global__ __launch_bounds__(256)
void scan3_kernel(const int* __restrict__ deg, const int* __restrict__ boff,
                  int* __restrict__ rowptr, int* __restrict__ cursor) {
  __shared__ int sh[256];
  int t = threadIdx.x, b = blockIdx.x;
  int idx = b * 256 + t;
  int v = deg[idx];
  sh[t] = v;
  __syncthreads();
  for (int off = 1; off < 256; off <<= 1) {
    int u = (t >= off) ? sh[t - off] : 0;
    __syncthreads();
    sh[t] += u;
    __syncthreads();
  }
  int ex = sh[t] - v + boff[b];
  rowptr[idx] = ex;
  cursor[idx] = ex;
}

__global__ void scatter_kernel(const int* __restrict__ src, const int* __restrict__ dst,
                               int* __restrict__ cursor, int* __restrict__ csr, int E) {
  int i = blockIdx.x * 256 + threadIdx.x;
  if (i < E) {
    int d = dst[i];
    int pos = atomicAdd(&cursor[d], 1);
    csr[pos] = src[i];
  }
}

// -------- aggregate neighbours (bf16 gather, 4-wide MLP) + (1+eps)*x --------
__global__ __launch_bounds__(256)
void agg_kernel(const u16* __restrict__ xb, const float* __restrict__ x,
                const int* __restrict__ csr, const int* __restrict__ rowptr,
                const float* __restrict__ eps, u16* __restrict__ hin, int N) {
  int node = blockIdx.x * 4 + (threadIdx.x >> 6);
  if (node >= N) return;
  int lane = threadIdx.x & 63;
  float ep1 = 1.0f + eps[0];
  int s0 = rowptr[node], s1 = rowptr[node + 1];
  float a0 = 0.f, a1 = 0.f;
  int e = s0;
  for (; e + 4 <= s1; e += 4) {
    int i0 = csr[e], i1 = csr[e + 1], i2 = csr[e + 2], i3 = csr[e + 3];
    u32 w0 = *(const u32*)(xb + (size_t)i0 * 128 + lane * 2);
    u32 w1 = *(const u32*)(xb + (size_t)i1 * 128 + lane * 2);
    u32 w2 = *(const u32*)(xb + (size_t)i2 * 128 + lane * 2);
    u32 w3 = *(const u32*)(xb + (size_t)i3 * 128 + lane * 2);
    a0 += b2f((u16)w0) + b2f((u16)w1) + b2f((u16)w2) + b2f((u16)w3);
    a1 += b2f((u16)(w0 >> 16)) + b2f((u16)(w1 >> 16))
        + b2f((u16)(w2 >> 16)) + b2f((u16)(w3 >> 16));
  }
  for (; e < s1; e++) {
    int s = csr[e];
    u32 w = *(const u32*)(xb + (size_t)s * 128 + lane * 2);
    a0 += b2f((u16)w);
    a1 += b2f((u16)(w >> 16));
  }
  float2 xw = *(const float2*)(x + (size_t)node * 128 + lane * 2);  // fp32 self-term
  a0 += ep1 * xw.x;
  a1 += ep1 * xw.y;
  *(u32*)(hin + (size_t)node * 128 + lane * 2) = (u32)f2b(a0) | ((u32)f2b(a1) << 16);
}

// ---------------- latency-optimized MFMA GEMM v2 ----------------
// Round-11 counters (49.5us/dispatch): MfmaUtil 1.5 / VALU 4.8 / HBM 8.8% /
// Occ 32% -> pure latency-bound, too few loads in flight and only 4 waves/SIMD
// of work for Nout=128. v2: 16x16 tile/wave (4x wave count), compile-time K,
// ALL frag loads issued in one burst before any MFMA (8-16 loads in flight),
// bf16 resid. headmajor scatters C to [b][h][j][dh] for attention.
template<int K>
__global__ __launch_bounds__(256)
void gemm_fast(const u16* __restrict__ A, const u16* __restrict__ Bt,
               const float* __restrict__ bias, const u16* __restrict__ residb,
               u16* __restrict__ C0, u16* __restrict__ C1, u16* __restrict__ C2,
               float* __restrict__ ssum, float* __restrict__ ssq,
               int ntshift, int relu, float scale0, int headmajor) {
  const int tid = threadIdx.x, wave = tid >> 6, lane = tid & 63;
  const int quad = lane >> 4, c = lane & 15;
  const int y = blockIdx.y;
  const int ti = y >> ntshift, nt = y & ((1 << ntshift) - 1);
  const int Nout = 16 << ntshift;
  const u16* Btp = Bt + (size_t)ti * Nout * K;
  const float* bp = bias + ti * Nout;
  u16* C = (ti == 0) ? C0 : ((ti == 1) ? C1 : C2);
  const float scl = (ti == 0) ? scale0 : 1.0f;
  const int row0 = blockIdx.x * 64 + wave * 16;
  const int col0 = nt * 16;

  const u16* Ap = A   + (size_t)(row0 + c) * K + quad * 8;
  const u16* Bp = Btp + (size_t)(col0 + c) * K + quad * 8;

  constexpr int NI = K / 32;
  short8 af[NI], bf[NI];
#pragma unroll
  for (int i = 0; i < NI; i++) {
    af[i] = *(const short8*)(Ap + i * 32);
    bf[i] = *(const short8*)(Bp + i * 32);
  }
  f32x4 acc = {0.f, 0.f, 0.f, 0.f};
#pragma unroll
  for (int i = 0; i < NI; i++)
    acc = __builtin_amdgcn_mfma_f32_16x16x32_bf16(af[i], bf[i], acc, 0, 0, 0);

  const int col = col0 + c;
  const float bv = bp[col];
  float sp = 0.f, qp = 0.f;
#pragma unroll
  for (int r = 0; r < 4; r++) {
    int m = row0 + quad * 4 + r;
    float v = acc[r] + bv;
    if (relu) v = fmaxf(v, 0.f);
    if (residb) v += b2f(residb[(size_t)m * Nout + col]);
    v *= scl;
    size_t cidx;
    if (headmajor) {
      int bb = m >> 9, j = m & 511;
      cidx = (size_t)(bb * 8 + (col >> 4)) * 8192 + (size_t)j * 16 + (col & 15);
    } else {
      cidx = (size_t)m * Nout + col;
    }
    C[cidx] = f2b(v);
    sp += v; qp += v * v;
  }
  if (ssum) {
    sp += __shfl_xor(sp, 16); sp += __shfl_xor(sp, 32);
    qp += __shfl_xor(qp, 16); qp += __shfl_xor(qp, 32);
    if (quad == 0) {
      atomicAdd(&ssum[col], sp);
      atomicAdd(&ssq[col], qp);
    }
  }
}

// ---------------- MFMA attention v5 (head-major Q/K/V) ----------------
__global__ __launch_bounds__(512)
void attn_kernel(const u16* __restrict__ Q, const u16* __restrict__ Km,
                 const u16* __restrict__ Vm, u16* __restrict__ O) {
  __shared__ __align__(16) u16 Ksh[512 * 24];   // K[j][k], row stride 24
  __shared__ __align__(16) u16 Vt[16 * 520];    // V^T [d][j'], row stride 520
  __shared__ __align__(16) u16 Psh[8][16 * 40]; // per-wave P
  const int bh = blockIdx.x >> 1, qhalf = blockIdx.x & 1;
  const int b = bh >> 3, hh = bh & 7;
  const size_t qkvbase = (size_t)bh * 8192;               // [b][h][512][16]
  const size_t obase   = (size_t)b * 512 * 128 + hh * 16; // [node][128]
  const int tid = threadIdx.x;

  {
    int j = tid;                         // 512 threads, one K/V row each (32B)
    short8 k0 = *(const short8*)(Km + qkvbase + (size_t)j * 16);
    short8 k1 = *(const short8*)(Km + qkvbase + (size_t)j * 16 + 8);
    short8 v0 = *(const short8*)(Vm + qkvbase + (size_t)j * 16);
    short8 v1 = *(const short8*)(Vm + qkvbase + (size_t)j * 16 + 8);
    *(short8*)&Ksh[j * 24]     = k0;
    *(short8*)&Ksh[j * 24 + 8] = k1;
    int jl = j & 31;
    int j2 = (j & ~31) | (((jl & 15) << 1) | (jl >> 4));   // interleaved j'
#pragma unroll
    for (int t = 0; t < 8; t++) Vt[t * 520 + j2] = (u16)v0[t];
#pragma unroll
    for (int t = 0; t < 8; t++) Vt[(8 + t) * 520 + j2] = (u16)v1[t];
  }
  __syncthreads();

  const int wave = tid >> 6, lane = tid & 63;
  const int quad = lane >> 4, c = lane & 15;
  u16* Pw = &Psh[wave][0];
  u32* Pw32 = (u32*)Pw;

  short8 ones;
#pragma unroll
  for (int i = 0; i < 8; i++) ones[i] = (short)0x3F80;   // bf16 1.0
  const f32x4 zero = {0.f, 0.f, 0.f, 0.f};

  for (int qt = qhalf * 16 + wave; qt < (qhalf + 1) * 16; qt += 8) {  // 2 iters
    short8 qfrag = (short8)0;
    if (quad < 2)
      qfrag = *(const short8*)(Q + qkvbase + (size_t)(qt * 16 + c) * 16 + quad * 8);

    f32x4 accO = zero, accL = zero;
    for (int jp = 0; jp < 16; jp++) {
      short8 kf0 = (short8)0, kf1 = (short8)0;
      if (quad < 2) {
        kf0 = *(const short8*)&Ksh[(jp * 32 + c) * 24 + quad * 8];
        kf1 = *(const short8*)&Ksh[(jp * 32 + 16 + c) * 24 + quad * 8];
      }
      f32x4 s0 = __builtin_amdgcn_mfma_f32_16x16x32_bf16(qfrag, kf0, zero, 0, 0, 0);
      f32x4 s1 = __builtin_amdgcn_mfma_f32_16x16x32_bf16(qfrag, kf1, zero, 0, 0, 0);
#pragma unroll
      for (int r = 0; r < 4; r++) {
        union { float f; u32 u; } u0, u1;
        u0.f = exp2f(s0[r]);
        u1.f = exp2f(s1[r]);
        Pw32[(quad * 4 + r) * 20 + c] = (u0.u >> 16) | (u1.u & 0xffff0000u);
      }
      short8 pf = *(const short8*)&Pw[c * 40 + quad * 8];
      short8 vf = *(const short8*)&Vt[c * 520 + jp * 32 + quad * 8];
      accO = __builtin_amdgcn_mfma_f32_16x16x32_bf16(pf, vf, accO, 0, 0, 0);
      accL = __builtin_amdgcn_mfma_f32_16x16x32_bf16(pf, ones, accL, 0, 0, 0);
    }
#pragma unroll
    for (int r = 0; r < 4; r++) {
      float o = accO[r] / accL[r];
      O[obase + (size_t)(qt * 16 + quad * 4 + r) * 128 + c] = f2b(o);
    }
  }
}

// ---------------- fused BN elementwise ----------------
__global__ __launch_bounds__(256)
void combine_kernel(const u16* __restrict__ y1, const u16* __restrict__ y2,
                    const float* __restrict__ stats,
                    const float* __restrict__ g1, const float* __restrict__ be1,
                    const float* __restrict__ g2, const float* __restrict__ be2,
                    u16* __restrict__ hout, float invM) {
  int i = blockIdx.x * 256 + threadIdx.x;
  int e0 = i * 2;
  int c = e0 & 127;
  float sc1a, sh1a, sc1b, sh1b, sc2a, sh2a, sc2b, sh2b;
  {
    float m = stats[c] * invM, vv = stats[128 + c] * invM - m * m;
    sc1a = g1[c] * rsqrtf(vv + 1e-5f); sh1a = be1[c] - m * sc1a;
    m = stats[c + 1] * invM; vv = stats[129 + c] * invM - m * m;
    sc1b = g1[c + 1] * rsqrtf(vv + 1e-5f); sh1b = be1[c + 1] - m * sc1b;
    m = stats[256 + c] * invM; vv = stats[384 + c] * invM - m * m;
    sc2a = g2[c] * rsqrtf(vv + 1e-5f); sh2a = be2[c] - m * sc2a;
    m = stats[257 + c] * invM; vv = stats[385 + c] * invM - m * m;
    sc2b = g2[c + 1] * rsqrtf(vv + 1e-5f); sh2b = be2[c + 1] - m * sc2b;
  }
  u32 w1 = *(const u32*)(y1 + e0);
  u32 w2 = *(const u32*)(y2 + e0);
  float r0 = b2f((u16)w1) * sc1a + sh1a + b2f((u16)w2) * sc2a + sh2a;
  float r1 = b2f((u16)(w1 >> 16)) * sc1b + sh1b + b2f((u16)(w2 >> 16)) * sc2b + sh2b;
  *(u32*)(hout + e0) = (u32)f2b(r0) | ((u32)f2b(r1) << 16);
}

// out = bn3(y3)  (bf16 in, fp32 out)
__global__ __launch_bounds__(256)
void norm_kernel(const u16* __restrict__ y3, const float* __restrict__ stats3,
                 const float* __restrict__ g3, const float* __restrict__ be3,
                 float* __restrict__ outp, float invM) {
  int i = blockIdx.x * 256 + threadIdx.x;
  int e0 = i * 2;
  int c = e0 & 127;
  float m = stats3[c] * invM, vv = stats3[128 + c] * invM - m * m;
  float sca = g3[c] * rsqrtf(vv + 1e-5f), sha = be3[c] - m * sca;
  m = stats3[c + 1] * invM; vv = stats3[129 + c] * invM - m * m;
  float scb = g3[c + 1] * rsqrtf(vv + 1e-5f), shb = be3[c + 1] - m * scb;
  u32 w = *(const u32*)(y3 + e0);
  float2 r;
  r.x = b2f((u16)w) * sca + sha;
  r.y = b2f((u16)(w >> 16)) * scb + shb;
  *(float2*)(outp + e0) = r;
}

// ---------------- launch ----------------
extern "C" void kernel_launch(void* const* d_in, const int* in_sizes, int n_in,
                              void* d_out, int out_size, void* d_ws, size_t ws_size,
                              hipStream_t stream) {
  const float* x   = (const float*)d_in[0];
  const int*   ei  = (const int*)d_in[1];
  const float* eps = (const float*)d_in[2];
  const float* Wl1 = (const float*)d_in[3];  const float* bl1 = (const float*)d_in[4];
  const float* Wl2 = (const float*)d_in[5];  const float* bl2 = (const float*)d_in[6];
  const float* g1  = (const float*)d_in[7];  const float* be1 = (const float*)d_in[8];
  const float* Wq  = (const float*)d_in[9];  const float* bq  = (const float*)d_in[10];
  const float* Wk  = (const float*)d_in[11]; const float* bk  = (const float*)d_in[12];
  const float* Wv  = (const float*)d_in[13]; const float* bv  = (const float*)d_in[14];
  const float* Wo  = (const float*)d_in[15]; const float* bo  = (const float*)d_in[16];
  const float* g2  = (const float*)d_in[17]; const float* be2 = (const float*)d_in[18];
  const float* Wf1 = (const float*)d_in[19]; const float* bf1 = (const float*)d_in[20];
  const float* Wf2 = (const float*)d_in[21]; const float* bf2 = (const float*)d_in[22];
  const float* g3  = (const float*)d_in[23]; const float* be3 = (const float*)d_in[24];
  float* out = (float*)d_out;

  const int N = in_sizes[0] / 128;   // 32768
  const int E = in_sizes[1] / 2;     // 524288
  const size_t MB = 1048576;
  const float invM = 1.0f / (float)N;

  char* ws = (char*)d_ws;
  u16* hin = (u16*)(ws + 0);          // [N,128] agg out; later o_attn
  u16* t1  = (u16*)(ws + 8 * MB);     // [N,256] hidden; later t2. CSR overlays pre-GEMM:
  int* deg    = (int*)(ws + 8 * MB);
  int* rowptr = (int*)(ws + 8 * MB + 256 * 1024);
  int* cursor = (int*)(ws + 8 * MB + 512 * 1024);
  int* csr    = (int*)(ws + 8 * MB + 768 * 1024);  // E ints = 2MB
  u16* qb  = (u16*)(ws + 24 * MB);    // q (head-major); later h_comb
  u16* kb  = (u16*)(ws + 32 * MB);    // k (head-major); later y3
  u16* vb  = (u16*)(ws + 40 * MB);    // v (head-major)
  u16* xb  = (u16*)(ws + 48 * MB);    // bf16 copy of x; later y2 (in-place resid)
  u16* y2  = xb;
  float* stats = (float*)(ws + 56 * MB);         // s1,q1,s2,q2,s3,q3 (6*128)
  int* bsum = (int*)(ws + 56 * MB + 8192);
  int* boff = (int*)(ws + 56 * MB + 8192 + 512);
  u16* y1 = (u16*)d_out;              // d_out[0..8MB) as bf16 scratch (rewritten by norm)
  u16*   BtAll   = (u16*)((char*)d_out + 8 * MB);                // 384 KB W^T stack
  float* biasAll = (float*)((char*)d_out + 8 * MB + 400 * 1024); // 5 KB

  hipMemsetAsync(deg, 0, (size_t)N * sizeof(int), stream);
  hipMemsetAsync(stats, 0, 6 * 128 * sizeof(float), stream);

  const int* srcv = ei;
  const int* dstv = ei + E;
  const float QSCL = 0.25f * 1.44269504088896f;   // score scale * log2(e)

  prep_kernel<<<774, 256, 0, stream>>>(Wl1, Wl2, Wq, Wk, Wv, Wo, Wf1, Wf2,
                                       bl1, bl2, bq, bk, bv, bo, bf1, bf2,
                                       BtAll, biasAll);
  f2bf_kernel<<<(N * 128 / 2) / 256, 256, 0, stream>>>(x, xb);
  hist_kernel<<<(E + 255) / 256, 256, 0, stream>>>(dstv, deg, E);
  scan1_kernel<<<N / 256, 256, 0, stream>>>(deg, bsum);
  scan2_kernel<<<1, 128, 0, stream>>>(bsum, boff, rowptr + N);
  scan3_kernel<<<N / 256, 256, 0, stream>>>(deg, boff, rowptr, cursor);
  scatter_kernel<<<(E + 255) / 256, 256, 0, stream>>>(srcv, dstv, cursor, csr, E);
  agg_kernel<<<N / 4, 256, 0, stream>>>(xb, x, csr, rowptr, eps, hin, N);

  dim3 blk(256);
  // t1 = relu(hin @ Wl1 + bl1)          Nout=256 (ntshift=4)
  gemm_fast<128><<<dim3(N / 64, 16), blk, 0, stream>>>(hin, BtAll + 0, biasAll + 0,
      nullptr, t1, nullptr, nullptr, nullptr, nullptr, 4, 1, 1.0f, 0);
  // y1 = xb + t1 @ Wl2 + bl2  (+stats1)  Nout=128
  gemm_fast<256><<<dim3(N / 64, 8), blk, 0, stream>>>(t1, BtAll + 32768, biasAll + 256,
      xb, y1, nullptr, nullptr, stats + 0, stats + 128, 3, 0, 1.0f, 0);
  // q,k,v fused (3 tensors), HEAD-MAJOR outputs; q pre-scaled by QSCL
  gemm_fast<128><<<dim3(N / 64, 24), blk, 0, stream>>>(xb, BtAll + 65536, biasAll + 384,
      nullptr, qb, kb, vb, nullptr, nullptr, 3, 0, QSCL, 1);
  // attention -> o_attn (reuse hin); grid = (b,h) x 2 q-halves
  attn_kernel<<<(N / 512) * 8 * 2, dim3(512), 0, stream>>>(qb, kb, vb, hin);
  // y2 = xb + o_attn @ Wo + bo  (+stats2)  (writes over xb in place, same-thread RMW)
  gemm_fast<128><<<dim3(N / 64, 8), blk, 0, stream>>>(hin, BtAll + 114688, biasAll + 768,
      xb, y2, nullptr, nullptr, stats + 256, stats + 384, 3, 0, 1.0f, 0);
  // h = bn1(y1) + bn2(y2)  -> qb   (BN params inline)
  combine_kernel<<<(N * 128 / 2) / 256, blk, 0, stream>>>(y1, y2, stats,
      g1, be1, g2, be2, qb, invM);
  // t2 = relu(h @ Wf1 + bf1)            Nout=256
  gemm_fast<128><<<dim3(N / 64, 16), blk, 0, stream>>>(qb, BtAll + 131072, biasAll + 896,
      nullptr, t1, nullptr, nullptr, nullptr, nullptr, 4, 1, 1.0f, 0);
  // y3 = qb + t2 @ Wf2 + bf2  (+stats3)  -> kb
  gemm_fast<256><<<dim3(N / 64, 8), blk, 0, stream>>>(t1, BtAll + 163840, biasAll + 1152,
      qb, kb, nullptr, nullptr, stats + 512, stats + 640, 3, 0, 1.0f, 0);
  // out = bn3(y3)   (BN params inline)
  norm_kernel<<<(N * 128 / 2) / 256, blk, 0, stream>>>(kb, stats + 512, g3, be3, out, invM);
}

// Round 13
// 430.265 us; speedup vs baseline: 1.6082x; 1.6082x over previous
//
#include <hip/hip_runtime.h>
#include <cstdint>
#include <cstddef>

typedef unsigned short u16;
typedef unsigned int u32;

using short8 = __attribute__((ext_vector_type(8))) short;
using f32x4  = __attribute__((ext_vector_type(4))) float;

// ---- MFMA-tile layout: tensor[M][NC] stored as [M/16][NC/32] tiles of
// [16 rows][32 cols] contiguous (512 el = 1KB). A wave's 16x16x32 frag load
// (lane c*32 + quad*8) is then one contiguous 1KB block -> perfectly
// coalesced, vs 16 scattered 64B segments in row-major (round-12 lesson:
// wall time scales with scattered-transaction count, not bytes/occupancy).
__device__ __forceinline__ size_t taddr(int m, int n, int nc32) {
  return ((size_t)(m >> 4) * nc32 + (n >> 5)) * 512 + (m & 15) * 32 + (n & 31);
}

__device__ __forceinline__ float b2f(u16 v) {
  union { u32 u; float f; } c; c.u = ((u32)v) << 16; return c.f;
}
__device__ __forceinline__ u16 f2b(float f) {
  union { float f; u32 u; } c; c.f = f;
  u32 u = c.u;
  u += 0x7fffu + ((u >> 16) & 1u);   // round-to-nearest-even
  return (u16)(u >> 16);
}

// ---------------- fp32 row-major -> bf16 tile-layout (128 cols) ----------------
__global__ __launch_bounds__(256)
void f2bf_kernel(const float* __restrict__ in, u16* __restrict__ outp) {
  int i = blockIdx.x * 256 + threadIdx.x;
  int el = i * 2;
  int m = ((el >> 11) << 4) | ((el >> 5) & 15);
  int n = (((el >> 9) & 3) << 5) | (el & 31);
  float2 v = *(const float2*)(in + (size_t)m * 128 + n);
  *(u32*)(outp + el) = (u32)f2b(v.x) | ((u32)f2b(v.y) << 16);
}

// ---------------- weight prep: W[K,N] fp32 -> Bt tile-layout bf16 ----------------
__global__ __launch_bounds__(256)
void prep_kernel(const float* __restrict__ Wl1, const float* __restrict__ Wl2,
                 const float* __restrict__ Wq,  const float* __restrict__ Wk,
                 const float* __restrict__ Wv,  const float* __restrict__ Wo,
                 const float* __restrict__ Wf1, const float* __restrict__ Wf2,
                 const float* __restrict__ bl1, const float* __restrict__ bl2,
                 const float* __restrict__ bq,  const float* __restrict__ bk,
                 const float* __restrict__ bv,  const float* __restrict__ bo,
                 const float* __restrict__ bf1, const float* __restrict__ bf2,
                 u16* __restrict__ Bt, float* __restrict__ biasAll) {
  int idx = blockIdx.x * 256 + threadIdx.x;
  if (idx < 196608) {
    const float* W; int local, K, N;
    if      (idx <  32768) { W = Wl1; local = idx;          K = 128; N = 256; }
    else if (idx <  65536) { W = Wl2; local = idx - 32768;  K = 256; N = 128; }
    else if (idx <  81920) { W = Wq;  local = idx - 65536;  K = 128; N = 128; }
    else if (idx <  98304) { W = Wk;  local = idx - 81920;  K = 128; N = 128; }
    else if (idx < 114688) { W = Wv;  local = idx - 98304;  K = 128; N = 128; }
    else if (idx < 131072) { W = Wo;  local = idx - 114688; K = 128; N = 128; }
    else if (idx < 163840) { W = Wf1; local = idx - 131072; K = 128; N = 256; }
    else                   { W = Wf2; local = idx - 163840; K = 256; N = 128; }
    // Bt tile layout over [N rows][K cols]: tiles (n>>4, k>>5)
    int ks2 = (K == 256) ? 3 : 2;          // k-tiles per n-tile-row
    int tile = local >> 9, within = local & 511;
    int nr = within >> 5, kc = within & 31;
    int n = ((tile >> ks2) << 4) + nr;
    int k = ((tile & ((1 << ks2) - 1)) << 5) + kc;
    Bt[idx] = f2b(W[(size_t)k * N + n]);
  }
  int t = idx - 196608;
  if (t >= 0 && t < 1280) {
    float v;
    if      (t <  256) v = bl1[t];
    else if (t <  384) v = bl2[t - 256];
    else if (t <  512) v = bq[t - 384];
    else if (t <  640) v = bk[t - 512];
    else if (t <  768) v = bv[t - 640];
    else if (t <  896) v = bo[t - 768];
    else if (t < 1152) v = bf1[t - 896];
    else               v = bf2[t - 1152];
    biasAll[t] = v;
  }
}

// ---------------- CSR build ----------------
__global__ void hist_kernel(const int* __restrict__ dst, int* __restrict__ deg, int E) {
  int i = blockIdx.x * 256 + threadIdx.x;
  if (i < E) atomicAdd(&deg[dst[i]], 1);
}

__global__ __launch_bounds__(256)
void scan1_kernel(const int* __restrict__ deg, int* __restrict__ bsum) {
  int t = threadIdx.x, b = blockIdx.x;
  int v = deg[b * 256 + t];
#pragma unroll
  for (int off = 1; off < 64; off <<= 1) v += __shfl_xor(v, off);
  __shared__ int wsum[4];
  if ((t & 63) == 0) wsum[t >> 6] = v;
  __syncthreads();
  if (t == 0) bsum[b] = wsum[0] + wsum[1] + wsum[2] + wsum[3];
}

__global__ void scan2_kernel(const int* __restrict__ bsum, int* __restrict__ boff,
                             int* __restrict__ rowptrN) {
  __shared__ int sh[128];
  int t = threadIdx.x;
  int v = bsum[t];
  sh[t] = v;
  __syncthreads();
  for (int off = 1; off < 128; off <<= 1) {
    int u = (t >= off) ? sh[t - off] : 0;
    __syncthreads();
    sh[t] += u;
    __syncthreads();
  }
  boff[t] = sh[t] - v;
  if (t == 127) *rowptrN = sh[127];
}

__global__ __launch_bounds__(256)
void scan3_kernel(const int* __restrict__ deg, const int* __restrict__ boff,
                  int* __restrict__ rowptr, int* __restrict__ cursor) {
  __shared__ int sh[256];
  int t = threadIdx.x, b = blockIdx.x;
  int idx = b * 256 + t;
  int v = deg[idx];
  sh[t] = v;
  __syncthreads();
  for (int off = 1; off < 256; off <<= 1) {
    int u = (t >= off) ? sh[t - off] : 0;
    __syncthreads();
    sh[t] += u;
    __syncthreads();
  }
  int ex = sh[t] - v + boff[b];
  rowptr[idx] = ex;
  cursor[idx] = ex;
}

__global__ void scatter_kernel(const int* __restrict__ src, const int* __restrict__ dst,
                               int* __restrict__ cursor, int* __restrict__ csr, int E) {
  int i = blockIdx.x * 256 + threadIdx.x;
  if (i < E) {
    int d = dst[i];
    int pos = atomicAdd(&cursor[d], 1);
    csr[pos] = src[i];
  }
}

// -------- aggregate neighbours (bf16 tile-layout gather) + (1+eps)*x --------
__global__ __launch_bounds__(256)
void agg_kernel(const u16* __restrict__ xb, const float* __restrict__ x,
                const int* __restrict__ csr, const int* __restrict__ rowptr,
                const float* __restrict__ eps, u16* __restrict__ hin, int N) {
  int node = blockIdx.x * 4 + (threadIdx.x >> 6);
  if (node >= N) return;
  int lane = threadIdx.x & 63;
  int laneoff = (lane >> 4) * 512 + (lane & 15) * 2;   // tile-layout lane part
  float ep1 = 1.0f + eps[0];
  int s0 = rowptr[node], s1 = rowptr[node + 1];
  float a0 = 0.f, a1 = 0.f;
  int e = s0;
  for (; e + 4 <= s1; e += 4) {
    int i0 = csr[e], i1 = csr[e + 1], i2 = csr[e + 2], i3 = csr[e + 3];
    u32 w0 = *(const u32*)(xb + (size_t)(i0 >> 4) * 2048 + (i0 & 15) * 32 + laneoff);
    u32 w1 = *(const u32*)(xb + (size_t)(i1 >> 4) * 2048 + (i1 & 15) * 32 + laneoff);
    u32 w2 = *(const u32*)(xb + (size_t)(i2 >> 4) * 2048 + (i2 & 15) * 32 + laneoff);
    u32 w3 = *(const u32*)(xb + (size_t)(i3 >> 4) * 2048 + (i3 & 15) * 32 + laneoff);
    a0 += b2f((u16)w0) + b2f((u16)w1) + b2f((u16)w2) + b2f((u16)w3);
    a1 += b2f((u16)(w0 >> 16)) + b2f((u16)(w1 >> 16))
        + b2f((u16)(w2 >> 16)) + b2f((u16)(w3 >> 16));
  }
  for (; e < s1; e++) {
    int s = csr[e];
    u32 w = *(const u32*)(xb + (size_t)(s >> 4) * 2048 + (s & 15) * 32 + laneoff);
    a0 += b2f((u16)w);
    a1 += b2f((u16)(w >> 16));
  }
  float2 xw = *(const float2*)(x + (size_t)node * 128 + lane * 2);  // fp32 self-term
  a0 += ep1 * xw.x;
  a1 += ep1 * xw.y;
  *(u32*)(hin + (size_t)(node >> 4) * 2048 + (node & 15) * 32 + laneoff)
      = (u32)f2b(a0) | ((u32)f2b(a1) << 16);
}

// ---------------- tile-layout MFMA GEMM v3 ----------------
// Round-11 32x32/wave compute structure (known good); A and Bt in tile
// layout -> every frag load is one contiguous 1KB block. Resid (bf16, 128
// cols, tile layout). headmajor scatters C to [b][h][j][dh] for attention.
template<int K>
__global__ __launch_bounds__(256)
void gemm_fast(const u16* __restrict__ A, const u16* __restrict__ Bt,
               const float* __restrict__ bias, const u16* __restrict__ residb,
               u16* __restrict__ C0, u16* __restrict__ C1, u16* __restrict__ C2,
               float* __restrict__ ssum, float* __restrict__ ssq,
               int ntshift, int relu, float scale0, int headmajor) {
  const int tid = threadIdx.x, wave = tid >> 6, lane = tid & 63;
  const int quad = lane >> 4, c = lane & 15;
  const int y = blockIdx.y;
  const int ti = y >> ntshift, ntv = y & ((1 << ntshift) - 1);
  const int Nout = 32 << ntshift;
  const int nc32 = 1 << (ntshift - 0) >> 0 ? (Nout >> 5) : 0;  // Nout/32
  constexpr int KT = K >> 5;
  const u16* Btp = Bt + (size_t)ti * Nout * K;
  const float* bp = bias + ti * Nout;
  u16* C = (ti == 0) ? C0 : ((ti == 1) ? C1 : C2);
  const float scl = (ti == 0) ? scale0 : 1.0f;
  const int row0 = blockIdx.x * 128 + wave * 32;
  const int mt0 = row0 >> 4;
  const int col0 = ntv * 32;
  const int loff = c * 32 + quad * 8;

  const u16* Ap0 = A   + (size_t)(mt0)     * KT * 512 + loff;
  const u16* Ap1 = A   + (size_t)(mt0 + 1) * KT * 512 + loff;
  const u16* Bp0 = Btp + (size_t)(ntv * 2)     * KT * 512 + loff;
  const u16* Bp1 = Btp + (size_t)(ntv * 2 + 1) * KT * 512 + loff;

  f32x4 acc[2][2];
#pragma unroll
  for (int i = 0; i < 2; i++)
#pragma unroll
    for (int j = 0; j < 2; j++)
#pragma unroll
      for (int r = 0; r < 4; r++) acc[i][j][r] = 0.f;

#pragma unroll
  for (int i = 0; i < KT; i++) {
    short8 a0 = *(const short8*)(Ap0 + i * 512);
    short8 a1 = *(const short8*)(Ap1 + i * 512);
    short8 b0 = *(const short8*)(Bp0 + i * 512);
    short8 b1 = *(const short8*)(Bp1 + i * 512);
    acc[0][0] = __builtin_amdgcn_mfma_f32_16x16x32_bf16(a0, b0, acc[0][0], 0, 0, 0);
    acc[0][1] = __builtin_amdgcn_mfma_f32_16x16x32_bf16(a0, b1, acc[0][1], 0, 0, 0);
    acc[1][0] = __builtin_amdgcn_mfma_f32_16x16x32_bf16(a1, b0, acc[1][0], 0, 0, 0);
    acc[1][1] = __builtin_amdgcn_mfma_f32_16x16x32_bf16(a1, b1, acc[1][1], 0, 0, 0);
  }

#pragma unroll
  for (int ci = 0; ci < 2; ci++) {
    int col = col0 + ci * 16 + c;
    float bv = bp[col];
    float sp = 0.f, qp = 0.f;
#pragma unroll
    for (int mi = 0; mi < 2; mi++) {
#pragma unroll
      for (int r = 0; r < 4; r++) {
        int m = row0 + mi * 16 + quad * 4 + r;
        float v = acc[mi][ci][r] + bv;
        if (relu) v = fmaxf(v, 0.f);
        if (residb)
          v += b2f(residb[((size_t)(mt0 + mi) * 4 + (col >> 5)) * 512
                          + (quad * 4 + r) * 32 + (col & 31)]);
        v *= scl;
        size_t cidx;
        if (headmajor) {
          int bb = m >> 9, j = m & 511;
          cidx = (size_t)(bb * 8 + (col >> 4)) * 8192 + (size_t)j * 16 + (col & 15);
        } else {
          cidx = ((size_t)(mt0 + mi) * nc32 + ntv) * 512
               + (quad * 4 + r) * 32 + ci * 16 + c;
        }
        C[cidx] = f2b(v);
        sp += v; qp += v * v;
      }
    }
    if (ssum) {
      sp += __shfl_xor(sp, 16); sp += __shfl_xor(sp, 32);
      qp += __shfl_xor(qp, 16); qp += __shfl_xor(qp, 32);
      if (quad == 0) {
        atomicAdd(&ssum[col], sp);
        atomicAdd(&ssq[col], qp);
      }
    }
  }
}

// ---------------- MFMA attention (head-major Q/K/V; O in tile layout) ----------------
__global__ __launch_bounds__(512)
void attn_kernel(const u16* __restrict__ Q, const u16* __restrict__ Km,
                 const u16* __restrict__ Vm, u16* __restrict__ O) {
  __shared__ __align__(16) u16 Ksh[512 * 24];   // K[j][k], row stride 24
  __shared__ __align__(16) u16 Vt[16 * 520];    // V^T [d][j'], row stride 520
  __shared__ __align__(16) u16 Psh[8][16 * 40]; // per-wave P
  const int bh = blockIdx.x >> 1, qhalf = blockIdx.x & 1;
  const int b = bh >> 3, hh = bh & 7;
  const size_t qkvbase = (size_t)bh * 8192;               // [b][h][512][16]
  const int tid = threadIdx.x;

  {
    int j = tid;                         // 512 threads, one K/V row each (32B)
    short8 k0 = *(const short8*)(Km + qkvbase + (size_t)j * 16);
    short8 k1 = *(const short8*)(Km + qkvbase + (size_t)j * 16 + 8);
    short8 v0 = *(const short8*)(Vm + qkvbase + (size_t)j * 16);
    short8 v1 = *(const short8*)(Vm + qkvbase + (size_t)j * 16 + 8);
    *(short8*)&Ksh[j * 24]     = k0;
    *(short8*)&Ksh[j * 24 + 8] = k1;
    int jl = j & 31;
    int j2 = (j & ~31) | (((jl & 15) << 1) | (jl >> 4));   // interleaved j'
#pragma unroll
    for (int t = 0; t < 8; t++) Vt[t * 520 + j2] = (u16)v0[t];
#pragma unroll
    for (int t = 0; t < 8; t++) Vt[(8 + t) * 520 + j2] = (u16)v1[t];
  }
  __syncthreads();

  const int wave = tid >> 6, lane = tid & 63;
  const int quad = lane >> 4, c = lane & 15;
  u16* Pw = &Psh[wave][0];
  u32* Pw32 = (u32*)Pw;

  short8 ones;
#pragma unroll
  for (int i = 0; i < 8; i++) ones[i] = (short)0x3F80;   // bf16 1.0
  const f32x4 zero = {0.f, 0.f, 0.f, 0.f};

  for (int qt = qhalf * 16 + wave; qt < (qhalf + 1) * 16; qt += 8) {  // 2 iters
    short8 qfrag = (short8)0;
    if (quad < 2)
      qfrag = *(const short8*)(Q + qkvbase + (size_t)(qt * 16 + c) * 16 + quad * 8);

    f32x4 accO = zero, accL = zero;
    for (int jp = 0; jp < 16; jp++) {
      short8 kf0 = (short8)0, kf1 = (short8)0;
      if (quad < 2) {
        kf0 = *(const short8*)&Ksh[(jp * 32 + c) * 24 + quad * 8];
        kf1 = *(const short8*)&Ksh[(jp * 32 + 16 + c) * 24 + quad * 8];
      }
      f32x4 s0 = __builtin_amdgcn_mfma_f32_16x16x32_bf16(qfrag, kf0, zero, 0, 0, 0);
      f32x4 s1 = __builtin_amdgcn_mfma_f32_16x16x32_bf16(qfrag, kf1, zero, 0, 0, 0);
#pragma unroll
      for (int r = 0; r < 4; r++) {
        union { float f; u32 u; } u0, u1;
        u0.f = exp2f(s0[r]);
        u1.f = exp2f(s1[r]);
        Pw32[(quad * 4 + r) * 20 + c] = (u0.u >> 16) | (u1.u & 0xffff0000u);
      }
      short8 pf = *(const short8*)&Pw[c * 40 + quad * 8];
      short8 vf = *(const short8*)&Vt[c * 520 + jp * 32 + quad * 8];
      accO = __builtin_amdgcn_mfma_f32_16x16x32_bf16(pf, vf, accO, 0, 0, 0);
      accL = __builtin_amdgcn_mfma_f32_16x16x32_bf16(pf, ones, accL, 0, 0, 0);
    }
    // O element (m = b*512 + qt*16 + quad*4 + r, n = hh*16 + c) in tile layout
#pragma unroll
    for (int r = 0; r < 4; r++) {
      float o = accO[r] / accL[r];
      size_t oidx = ((size_t)(b * 32 + qt) * 4 + (hh >> 1)) * 512
                  + (quad * 4 + r) * 32 + (hh & 1) * 16 + c;
      O[oidx] = f2b(o);
    }
  }
}

// ---------------- fused BN elementwise (tile layout in/out) ----------------
__global__ __launch_bounds__(256)
void combine_kernel(const u16* __restrict__ y1, const u16* __restrict__ y2,
                    const float* __restrict__ stats,
                    const float* __restrict__ g1, const float* __restrict__ be1,
                    const float* __restrict__ g2, const float* __restrict__ be2,
                    u16* __restrict__ hout, float invM) {
  int i = blockIdx.x * 256 + threadIdx.x;
  int e0 = i * 2;
  int c = (((e0 >> 9) & 3) << 5) | (e0 & 31);   // column in [0,128)
  float sc1a, sh1a, sc1b, sh1b, sc2a, sh2a, sc2b, sh2b;
  {
    float m = stats[c] * invM, vv = stats[128 + c] * invM - m * m;
    sc1a = g1[c] * rsqrtf(vv + 1e-5f); sh1a = be1[c] - m * sc1a;
    m = stats[c + 1] * invM; vv = stats[129 + c] * invM - m * m;
    sc1b = g1[c + 1] * rsqrtf(vv + 1e-5f); sh1b = be1[c + 1] - m * sc1b;
    m = stats[256 + c] * invM; vv = stats[384 + c] * invM - m * m;
    sc2a = g2[c] * rsqrtf(vv + 1e-5f); sh2a = be2[c] - m * sc2a;
    m = stats[257 + c] * invM; vv = stats[385 + c] * invM - m * m;
    sc2b = g2[c + 1] * rsqrtf(vv + 1e-5f); sh2b = be2[c + 1] - m * sc2b;
  }
  u32 w1 = *(const u32*)(y1 + e0);
  u32 w2 = *(const u32*)(y2 + e0);
  float r0 = b2f((u16)w1) * sc1a + sh1a + b2f((u16)w2) * sc2a + sh2a;
  float r1 = b2f((u16)(w1 >> 16)) * sc1b + sh1b + b2f((u16)(w2 >> 16)) * sc2b + sh2b;
  *(u32*)(hout + e0) = (u32)f2b(r0) | ((u32)f2b(r1) << 16);
}

// out = bn3(y3): y3 tile layout, out row-major fp32
__global__ __launch_bounds__(256)
void norm_kernel(const u16* __restrict__ y3, const float* __restrict__ stats3,
                 const float* __restrict__ g3, const float* __restrict__ be3,
                 float* __restrict__ outp, float invM) {
  int i = blockIdx.x * 256 + threadIdx.x;
  int e0 = i * 2;
  int m = ((e0 >> 11) << 4) | ((e0 >> 5) & 15);
  int c = (((e0 >> 9) & 3) << 5) | (e0 & 31);
  float mm = stats3[c] * invM, vv = stats3[128 + c] * invM - mm * mm;
  float sca = g3[c] * rsqrtf(vv + 1e-5f), sha = be3[c] - mm * sca;
  mm = stats3[c + 1] * invM; vv = stats3[129 + c] * invM - mm * mm;
  float scb = g3[c + 1] * rsqrtf(vv + 1e-5f), shb = be3[c + 1] - mm * scb;
  u32 w = *(const u32*)(y3 + e0);
  float2 r;
  r.x = b2f((u16)w) * sca + sha;
  r.y = b2f((u16)(w >> 16)) * scb + shb;
  *(float2*)(outp + (size_t)m * 128 + c) = r;
}

// ---------------- launch ----------------
extern "C" void kernel_launch(void* const* d_in, const int* in_sizes, int n_in,
                              void* d_out, int out_size, void* d_ws, size_t ws_size,
                              hipStream_t stream) {
  const float* x   = (const float*)d_in[0];
  const int*   ei  = (const int*)d_in[1];
  const float* eps = (const float*)d_in[2];
  const float* Wl1 = (const float*)d_in[3];  const float* bl1 = (const float*)d_in[4];
  const float* Wl2 = (const float*)d_in[5];  const float* bl2 = (const float*)d_in[6];
  const float* g1  = (const float*)d_in[7];  const float* be1 = (const float*)d_in[8];
  const float* Wq  = (const float*)d_in[9];  const float* bq  = (const float*)d_in[10];
  const float* Wk  = (const float*)d_in[11]; const float* bk  = (const float*)d_in[12];
  const float* Wv  = (const float*)d_in[13]; const float* bv  = (const float*)d_in[14];
  const float* Wo  = (const float*)d_in[15]; const float* bo  = (const float*)d_in[16];
  const float* g2  = (const float*)d_in[17]; const float* be2 = (const float*)d_in[18];
  const float* Wf1 = (const float*)d_in[19]; const float* bf1 = (const float*)d_in[20];
  const float* Wf2 = (const float*)d_in[21]; const float* bf2 = (const float*)d_in[22];
  const float* g3  = (const float*)d_in[23]; const float* be3 = (const float*)d_in[24];
  float* out = (float*)d_out;

  const int N = in_sizes[0] / 128;   // 32768
  const int E = in_sizes[1] / 2;     // 524288
  const size_t MB = 1048576;
  const float invM = 1.0f / (float)N;

  char* ws = (char*)d_ws;
  u16* hin = (u16*)(ws + 0);          // [N,128] tile; agg out, later o_attn
  u16* t1  = (u16*)(ws + 8 * MB);     // [N,256] tile; later t2. CSR overlays pre-GEMM:
  int* deg    = (int*)(ws + 8 * MB);
  int* rowptr = (int*)(ws + 8 * MB + 256 * 1024);
  int* cursor = (int*)(ws + 8 * MB + 512 * 1024);
  int* csr    = (int*)(ws + 8 * MB + 768 * 1024);  // E ints = 2MB
  u16* qb  = (u16*)(ws + 24 * MB);    // q (head-major); later h_comb (tile)
  u16* kb  = (u16*)(ws + 32 * MB);    // k (head-major); later y3 (tile)
  u16* vb  = (u16*)(ws + 40 * MB);    // v (head-major)
  u16* xb  = (u16*)(ws + 48 * MB);    // bf16 x (tile); later y2 in-place
  u16* y2  = xb;
  float* stats = (float*)(ws + 56 * MB);         // s1,q1,s2,q2,s3,q3 (6*128)
  int* bsum = (int*)(ws + 56 * MB + 8192);
  int* boff = (int*)(ws + 56 * MB + 8192 + 512);
  u16* y1 = (u16*)d_out;              // d_out[0..8MB) as bf16 tile scratch
  u16*   BtAll   = (u16*)((char*)d_out + 8 * MB);                // 384 KB W^T tiles
  float* biasAll = (float*)((char*)d_out + 8 * MB + 400 * 1024); // 5 KB

  hipMemsetAsync(deg, 0, (size_t)N * sizeof(int), stream);
  hipMemsetAsync(stats, 0, 6 * 128 * sizeof(float), stream);

  const int* srcv = ei;
  const int* dstv = ei + E;
  const float QSCL = 0.25f * 1.44269504088896f;   // score scale * log2(e)

  prep_kernel<<<774, 256, 0, stream>>>(Wl1, Wl2, Wq, Wk, Wv, Wo, Wf1, Wf2,
                                       bl1, bl2, bq, bk, bv, bo, bf1, bf2,
                                       BtAll, biasAll);
  f2bf_kernel<<<(N * 128 / 2) / 256, 256, 0, stream>>>(x, xb);
  hist_kernel<<<(E + 255) / 256, 256, 0, stream>>>(dstv, deg, E);
  scan1_kernel<<<N / 256, 256, 0, stream>>>(deg, bsum);
  scan2_kernel<<<1, 128, 0, stream>>>(bsum, boff, rowptr + N);
  scan3_kernel<<<N / 256, 256, 0, stream>>>(deg, boff, rowptr, cursor);
  scatter_kernel<<<(E + 255) / 256, 256, 0, stream>>>(srcv, dstv, cursor, csr, E);
  agg_kernel<<<N / 4, 256, 0, stream>>>(xb, x, csr, rowptr, eps, hin, N);

  dim3 blk(256);
  // t1 = relu(hin @ Wl1 + bl1)          Nout=256 (ntshift=3)
  gemm_fast<128><<<dim3(N / 128, 8), blk, 0, stream>>>(hin, BtAll + 0, biasAll + 0,
      nullptr, t1, nullptr, nullptr, nullptr, nullptr, 3, 1, 1.0f, 0);
  // y1 = xb + t1 @ Wl2 + bl2  (+stats1)  Nout=128
  gemm_fast<256><<<dim3(N / 128, 4), blk, 0, stream>>>(t1, BtAll + 32768, biasAll + 256,
      xb, y1, nullptr, nullptr, stats + 0, stats + 128, 2, 0, 1.0f, 0);
  // q,k,v fused (3 tensors), HEAD-MAJOR outputs; q pre-scaled by QSCL
  gemm_fast<128><<<dim3(N / 128, 12), blk, 0, stream>>>(xb, BtAll + 65536, biasAll + 384,
      nullptr, qb, kb, vb, nullptr, nullptr, 2, 0, QSCL, 1);
  // attention -> o_attn (tile layout, reuse hin); grid = (b,h) x 2 q-halves
  attn_kernel<<<(N / 512) * 8 * 2, dim3(512), 0, stream>>>(qb, kb, vb, hin);
  // y2 = xb + o_attn @ Wo + bo  (+stats2)  (in-place over xb, same-thread RMW)
  gemm_fast<128><<<dim3(N / 128, 4), blk, 0, stream>>>(hin, BtAll + 114688, biasAll + 768,
      xb, y2, nullptr, nullptr, stats + 256, stats + 384, 2, 0, 1.0f, 0);
  // h = bn1(y1) + bn2(y2)  -> qb   (BN params inline)
  combine_kernel<<<(N * 128 / 2) / 256, blk, 0, stream>>>(y1, y2, stats,
      g1, be1, g2, be2, qb, invM);
  // t2 = relu(h @ Wf1 + bf1)            Nout=256
  gemm_fast<128><<<dim3(N / 128, 8), blk, 0, stream>>>(qb, BtAll + 131072, biasAll + 896,
      nullptr, t1, nullptr, nullptr, nullptr, nullptr, 3, 1, 1.0f, 0);
  // y3 = qb + t2 @ Wf2 + bf2  (+stats3)  -> kb
  gemm_fast<256><<<dim3(N / 128, 4), blk, 0, stream>>>(t1, BtAll + 163840, biasAll + 1152,
      qb, kb, nullptr, nullptr, stats + 512, stats + 640, 2, 0, 1.0f, 0);
  // out = bn3(y3)   (BN params inline)
  norm_kernel<<<(N * 128 / 2) / 256, blk, 0, stream>>>(kb, stats + 512, g3, be3, out, invM);
}

// Round 14
// 426.092 us; speedup vs baseline: 1.6239x; 1.0098x over previous
//
#include <hip/hip_runtime.h>
#include <cstdint>
#include <cstddef>

typedef unsigned short u16;
typedef unsigned int u32;

using short8 = __attribute__((ext_vector_type(8))) short;
using f32x4  = __attribute__((ext_vector_type(4))) float;

// ---- MFMA-tile layout: tensor[M][NC] stored as [M/16][NC/32] tiles of
// [16 rows][32 cols] contiguous (512 el = 1KB). A wave's 16x16x32 frag load
// is then one contiguous 1KB block (round-12 lesson: wall time scales with
// scattered-transaction count, not bytes/occupancy).
__device__ __forceinline__ float b2f(u16 v) {
  union { u32 u; float f; } c; c.u = ((u32)v) << 16; return c.f;
}
__device__ __forceinline__ u16 f2b(float f) {
  union { float f; u32 u; } c; c.f = f;
  u32 u = c.u;
  u += 0x7fffu + ((u >> 16) & 1u);   // round-to-nearest-even
  return (u16)(u >> 16);
}

// ---------------- fp32 row-major -> bf16 tile-layout (128 cols) ----------------
__global__ __launch_bounds__(256)
void f2bf_kernel(const float* __restrict__ in, u16* __restrict__ outp) {
  int i = blockIdx.x * 256 + threadIdx.x;
  int el = i * 2;
  int m = ((el >> 11) << 4) | ((el >> 5) & 15);
  int n = (((el >> 9) & 3) << 5) | (el & 31);
  float2 v = *(const float2*)(in + (size_t)m * 128 + n);
  *(u32*)(outp + el) = (u32)f2b(v.x) | ((u32)f2b(v.y) << 16);
}

// ---------------- weight prep: W[K,N] fp32 -> Bt tile-layout bf16 ----------------
__global__ __launch_bounds__(256)
void prep_kernel(const float* __restrict__ Wl1, const float* __restrict__ Wl2,
                 const float* __restrict__ Wq,  const float* __restrict__ Wk,
                 const float* __restrict__ Wv,  const float* __restrict__ Wo,
                 const float* __restrict__ Wf1, const float* __restrict__ Wf2,
                 const float* __restrict__ bl1, const float* __restrict__ bl2,
                 const float* __restrict__ bq,  const float* __restrict__ bk,
                 const float* __restrict__ bv,  const float* __restrict__ bo,
                 const float* __restrict__ bf1, const float* __restrict__ bf2,
                 u16* __restrict__ Bt, float* __restrict__ biasAll) {
  int idx = blockIdx.x * 256 + threadIdx.x;
  if (idx < 196608) {
    const float* W; int local, K, N;
    if      (idx <  32768) { W = Wl1; local = idx;          K = 128; N = 256; }
    else if (idx <  65536) { W = Wl2; local = idx - 32768;  K = 256; N = 128; }
    else if (idx <  81920) { W = Wq;  local = idx - 65536;  K = 128; N = 128; }
    else if (idx <  98304) { W = Wk;  local = idx - 81920;  K = 128; N = 128; }
    else if (idx < 114688) { W = Wv;  local = idx - 98304;  K = 128; N = 128; }
    else if (idx < 131072) { W = Wo;  local = idx - 114688; K = 128; N = 128; }
    else if (idx < 163840) { W = Wf1; local = idx - 131072; K = 128; N = 256; }
    else                   { W = Wf2; local = idx - 163840; K = 256; N = 128; }
    int ks2 = (K == 256) ? 3 : 2;          // k-tiles per n-tile-row
    int tile = local >> 9, within = local & 511;
    int nr = within >> 5, kc = within & 31;
    int n = ((tile >> ks2) << 4) + nr;
    int k = ((tile & ((1 << ks2) - 1)) << 5) + kc;
    Bt[idx] = f2b(W[(size_t)k * N + n]);
  }
  int t = idx - 196608;
  if (t >= 0 && t < 1280) {
    float v;
    if      (t <  256) v = bl1[t];
    else if (t <  384) v = bl2[t - 256];
    else if (t <  512) v = bq[t - 384];
    else if (t <  640) v = bk[t - 512];
    else if (t <  768) v = bv[t - 640];
    else if (t <  896) v = bo[t - 768];
    else if (t < 1152) v = bf1[t - 896];
    else               v = bf2[t - 1152];
    biasAll[t] = v;
  }
}

// ---------------- CSR build ----------------
__global__ void hist_kernel(const int* __restrict__ dst, int* __restrict__ deg, int E) {
  int i = blockIdx.x * 256 + threadIdx.x;
  if (i < E) atomicAdd(&deg[dst[i]], 1);
}

__global__ __launch_bounds__(256)
void scan1_kernel(const int* __restrict__ deg, int* __restrict__ bsum) {
  int t = threadIdx.x, b = blockIdx.x;
  int v = deg[b * 256 + t];
#pragma unroll
  for (int off = 1; off < 64; off <<= 1) v += __shfl_xor(v, off);
  __shared__ int wsum[4];
  if ((t & 63) == 0) wsum[t >> 6] = v;
  __syncthreads();
  if (t == 0) bsum[b] = wsum[0] + wsum[1] + wsum[2] + wsum[3];
}

__global__ void scan2_kernel(const int* __restrict__ bsum, int* __restrict__ boff,
                             int* __restrict__ rowptrN) {
  __shared__ int sh[128];
  int t = threadIdx.x;
  int v = bsum[t];
  sh[t] = v;
  __syncthreads();
  for (int off = 1; off < 128; off <<= 1) {
    int u = (t >= off) ? sh[t - off] : 0;
    __syncthreads();
    sh[t] += u;
    __syncthreads();
  }
  boff[t] = sh[t] - v;
  if (t == 127) *rowptrN = sh[127];
}

__global__ __launch_bounds__(256)
void scan3_kernel(const int* __restrict__ deg, const int* __restrict__ boff,
                  int* __restrict__ rowptr, int* __restrict__ cursor) {
  __shared__ int sh[256];
  int t = threadIdx.x, b = blockIdx.x;
  int idx = b * 256 + t;
  int v = deg[idx];
  sh[t] = v;
  __syncthreads();
  for (int off = 1; off < 256; off <<= 1) {
    int u = (t >= off) ? sh[t - off] : 0;
    __syncthreads();
    sh[t] += u;
    __syncthreads();
  }
  int ex = sh[t] - v + boff[b];
  rowptr[idx] = ex;
  cursor[idx] = ex;
}

__global__ void scatter_kernel(const int* __restrict__ src, const int* __restrict__ dst,
                               int* __restrict__ cursor, int* __restrict__ csr, int E) {
  int i = blockIdx.x * 256 + threadIdx.x;
  if (i < E) {
    int d = dst[i];
    int pos = atomicAdd(&cursor[d], 1);
    csr[pos] = src[i];
  }
}

// -------- aggregate neighbours (bf16 tile-layout gather) + (1+eps)*x --------
__global__ __launch_bounds__(256)
void agg_kernel(const u16* __restrict__ xb, const float* __restrict__ x,
                const int* __restrict__ csr, const int* __restrict__ rowptr,
                const float* __restrict__ eps, u16* __restrict__ hin, int N) {
  int node = blockIdx.x * 4 + (threadIdx.x >> 6);
  if (node >= N) return;
  int lane = threadIdx.x & 63;
  int laneoff = (lane >> 4) * 512 + (lane & 15) * 2;   // tile-layout lane part
  float ep1 = 1.0f + eps[0];
  int s0 = rowptr[node], s1 = rowptr[node + 1];
  float a0 = 0.f, a1 = 0.f;
  int e = s0;
  for (; e + 4 <= s1; e += 4) {
    int i0 = csr[e], i1 = csr[e + 1], i2 = csr[e + 2], i3 = csr[e + 3];
    u32 w0 = *(const u32*)(xb + (size_t)(i0 >> 4) * 2048 + (i0 & 15) * 32 + laneoff);
    u32 w1 = *(const u32*)(xb + (size_t)(i1 >> 4) * 2048 + (i1 & 15) * 32 + laneoff);
    u32 w2 = *(const u32*)(xb + (size_t)(i2 >> 4) * 2048 + (i2 & 15) * 32 + laneoff);
    u32 w3 = *(const u32*)(xb + (size_t)(i3 >> 4) * 2048 + (i3 & 15) * 32 + laneoff);
    a0 += b2f((u16)w0) + b2f((u16)w1) + b2f((u16)w2) + b2f((u16)w3);
    a1 += b2f((u16)(w0 >> 16)) + b2f((u16)(w1 >> 16))
        + b2f((u16)(w2 >> 16)) + b2f((u16)(w3 >> 16));
  }
  for (; e < s1; e++) {
    int s = csr[e];
    u32 w = *(const u32*)(xb + (size_t)(s >> 4) * 2048 + (s & 15) * 32 + laneoff);
    a0 += b2f((u16)w);
    a1 += b2f((u16)(w >> 16));
  }
  float2 xw = *(const float2*)(x + (size_t)node * 128 + lane * 2);  // fp32 self-term
  a0 += ep1 * xw.x;
  a1 += ep1 * xw.y;
  *(u32*)(hin + (size_t)(node >> 4) * 2048 + (node & 15) * 32 + laneoff)
      = (u32)f2b(a0) | ((u32)f2b(a1) << 16);
}

// ---------------- tile-layout MFMA GEMM v3 (round-13, unchanged) ----------------
template<int K>
__global__ __launch_bounds__(256)
void gemm_fast(const u16* __restrict__ A, const u16* __restrict__ Bt,
               const float* __restrict__ bias, const u16* __restrict__ residb,
               u16* __restrict__ C0, u16* __restrict__ C1, u16* __restrict__ C2,
               float* __restrict__ ssum, float* __restrict__ ssq,
               int ntshift, int relu, float scale0, int headmajor) {
  const int tid = threadIdx.x, wave = tid >> 6, lane = tid & 63;
  const int quad = lane >> 4, c = lane & 15;
  const int y = blockIdx.y;
  const int ti = y >> ntshift, ntv = y & ((1 << ntshift) - 1);
  const int Nout = 32 << ntshift;
  const int nc32 = Nout >> 5;
  constexpr int KT = K >> 5;
  const u16* Btp = Bt + (size_t)ti * Nout * K;
  const float* bp = bias + ti * Nout;
  u16* C = (ti == 0) ? C0 : ((ti == 1) ? C1 : C2);
  const float scl = (ti == 0) ? scale0 : 1.0f;
  const int row0 = blockIdx.x * 128 + wave * 32;
  const int mt0 = row0 >> 4;
  const int col0 = ntv * 32;
  const int loff = c * 32 + quad * 8;

  const u16* Ap0 = A   + (size_t)(mt0)     * KT * 512 + loff;
  const u16* Ap1 = A   + (size_t)(mt0 + 1) * KT * 512 + loff;
  const u16* Bp0 = Btp + (size_t)(ntv * 2)     * KT * 512 + loff;
  const u16* Bp1 = Btp + (size_t)(ntv * 2 + 1) * KT * 512 + loff;

  f32x4 acc[2][2];
#pragma unroll
  for (int i = 0; i < 2; i++)
#pragma unroll
    for (int j = 0; j < 2; j++)
#pragma unroll
      for (int r = 0; r < 4; r++) acc[i][j][r] = 0.f;

#pragma unroll
  for (int i = 0; i < KT; i++) {
    short8 a0 = *(const short8*)(Ap0 + i * 512);
    short8 a1 = *(const short8*)(Ap1 + i * 512);
    short8 b0 = *(const short8*)(Bp0 + i * 512);
    short8 b1 = *(const short8*)(Bp1 + i * 512);
    acc[0][0] = __builtin_amdgcn_mfma_f32_16x16x32_bf16(a0, b0, acc[0][0], 0, 0, 0);
    acc[0][1] = __builtin_amdgcn_mfma_f32_16x16x32_bf16(a0, b1, acc[0][1], 0, 0, 0);
    acc[1][0] = __builtin_amdgcn_mfma_f32_16x16x32_bf16(a1, b0, acc[1][0], 0, 0, 0);
    acc[1][1] = __builtin_amdgcn_mfma_f32_16x16x32_bf16(a1, b1, acc[1][1], 0, 0, 0);
  }

#pragma unroll
  for (int ci = 0; ci < 2; ci++) {
    int col = col0 + ci * 16 + c;
    float bv = bp[col];
    float sp = 0.f, qp = 0.f;
#pragma unroll
    for (int mi = 0; mi < 2; mi++) {
#pragma unroll
      for (int r = 0; r < 4; r++) {
        int m = row0 + mi * 16 + quad * 4 + r;
        float v = acc[mi][ci][r] + bv;
        if (relu) v = fmaxf(v, 0.f);
        if (residb)
          v += b2f(residb[((size_t)(mt0 + mi) * 4 + (col >> 5)) * 512
                          + (quad * 4 + r) * 32 + (col & 31)]);
        v *= scl;
        size_t cidx;
        if (headmajor) {
          int bb = m >> 9, j = m & 511;
          cidx = (size_t)(bb * 8 + (col >> 4)) * 8192 + (size_t)j * 16 + (col & 15);
        } else {
          cidx = ((size_t)(mt0 + mi) * nc32 + ntv) * 512
               + (quad * 4 + r) * 32 + ci * 16 + c;
        }
        C[cidx] = f2b(v);
        sp += v; qp += v * v;
      }
    }
    if (ssum) {
      sp += __shfl_xor(sp, 16); sp += __shfl_xor(sp, 32);
      qp += __shfl_xor(qp, 16); qp += __shfl_xor(qp, 32);
      if (quad == 0) {
        atomicAdd(&ssum[col], sp);
        atomicAdd(&ssq[col], qp);
      }
    }
  }
}

// ---------------- MFMA attention v6 ----------------
// Round-13 counters: attn latency-bound (VALU 62%, Occ 47%, HBM 7%) —
// LDS 51.7KB caps residency at 3 blocks/CU. v6 drops Ksh: K-frags read
// straight from global head-major layout, where a frag load is one
// contiguous 512B block (round-9's global-K regression was caused by the
// old strided [node][128] layout — FETCH guardrail: expect ~20-28MB, not 82).
// LDS 26.9KB + VGPR<=64 -> 4 blocks/CU = 32 waves/CU ceiling.
__global__ __launch_bounds__(512)
void attn_kernel(const u16* __restrict__ Q, const u16* __restrict__ Km,
                 const u16* __restrict__ Vm, u16* __restrict__ O) {
  __shared__ __align__(16) u16 Vt[16 * 520];    // V^T [d][j'], row stride 520
  __shared__ __align__(16) u16 Psh[8][16 * 40]; // per-wave P
  const int bh = blockIdx.x >> 1, qhalf = blockIdx.x & 1;
  const int b = bh >> 3, hh = bh & 7;
  const size_t qkvbase = (size_t)bh * 8192;               // [b][h][512][16]
  const int tid = threadIdx.x;

  {
    int j = tid;                         // 512 threads, one V row each (32B)
    short8 v0 = *(const short8*)(Vm + qkvbase + (size_t)j * 16);
    short8 v1 = *(const short8*)(Vm + qkvbase + (size_t)j * 16 + 8);
    int jl = j & 31;
    int j2 = (j & ~31) | (((jl & 15) << 1) | (jl >> 4));   // interleaved j'
#pragma unroll
    for (int t = 0; t < 8; t++) Vt[t * 520 + j2] = (u16)v0[t];
#pragma unroll
    for (int t = 0; t < 8; t++) Vt[(8 + t) * 520 + j2] = (u16)v1[t];
  }
  __syncthreads();

  const int wave = tid >> 6, lane = tid & 63;
  const int quad = lane >> 4, c = lane & 15;
  u16* Pw = &Psh[wave][0];
  u32* Pw32 = (u32*)Pw;

  short8 ones;
#pragma unroll
  for (int i = 0; i < 8; i++) ones[i] = (short)0x3F80;   // bf16 1.0
  const f32x4 zero = {0.f, 0.f, 0.f, 0.f};

  for (int qt = qhalf * 16 + wave; qt < (qhalf + 1) * 16; qt += 8) {  // 2 iters
    short8 qfrag = (short8)0;
    if (quad < 2)
      qfrag = *(const short8*)(Q + qkvbase + (size_t)(qt * 16 + c) * 16 + quad * 8);

    f32x4 accO = zero, accL = zero;
#pragma unroll 2
    for (int jp = 0; jp < 16; jp++) {
      short8 kf0 = (short8)0, kf1 = (short8)0;
      if (quad < 2) {
        // head-major: rows jp*32+c / +16, contiguous 512B per frag
        kf0 = *(const short8*)(Km + qkvbase + (size_t)(jp * 32 + c) * 16 + quad * 8);
        kf1 = *(const short8*)(Km + qkvbase + (size_t)(jp * 32 + 16 + c) * 16 + quad * 8);
      }
      f32x4 s0 = __builtin_amdgcn_mfma_f32_16x16x32_bf16(qfrag, kf0, zero, 0, 0, 0);
      f32x4 s1 = __builtin_amdgcn_mfma_f32_16x16x32_bf16(qfrag, kf1, zero, 0, 0, 0);
#pragma unroll
      for (int r = 0; r < 4; r++) {
        union { float f; u32 u; } u0, u1;
        u0.f = exp2f(s0[r]);
        u1.f = exp2f(s1[r]);
        Pw32[(quad * 4 + r) * 20 + c] = (u0.u >> 16) | (u1.u & 0xffff0000u);
      }
      short8 pf = *(const short8*)&Pw[c * 40 + quad * 8];
      short8 vf = *(const short8*)&Vt[c * 520 + jp * 32 + quad * 8];
      accO = __builtin_amdgcn_mfma_f32_16x16x32_bf16(pf, vf, accO, 0, 0, 0);
      accL = __builtin_amdgcn_mfma_f32_16x16x32_bf16(pf, ones, accL, 0, 0, 0);
    }
    // O element (m = b*512 + qt*16 + quad*4 + r, n = hh*16 + c) in tile layout
#pragma unroll
    for (int r = 0; r < 4; r++) {
      float o = accO[r] / accL[r];
      size_t oidx = ((size_t)(b * 32 + qt) * 4 + (hh >> 1)) * 512
                  + (quad * 4 + r) * 32 + (hh & 1) * 16 + c;
      O[oidx] = f2b(o);
    }
  }
}

// ---------------- fused BN elementwise (tile layout in/out) ----------------
__global__ __launch_bounds__(256)
void combine_kernel(const u16* __restrict__ y1, const u16* __restrict__ y2,
                    const float* __restrict__ stats,
                    const float* __restrict__ g1, const float* __restrict__ be1,
                    const float* __restrict__ g2, const float* __restrict__ be2,
                    u16* __restrict__ hout, float invM) {
  int i = blockIdx.x * 256 + threadIdx.x;
  int e0 = i * 2;
  int c = (((e0 >> 9) & 3) << 5) | (e0 & 31);   // column in [0,128)
  float sc1a, sh1a, sc1b, sh1b, sc2a, sh2a, sc2b, sh2b;
  {
    float m = stats[c] * invM, vv = stats[128 + c] * invM - m * m;
    sc1a = g1[c] * rsqrtf(vv + 1e-5f); sh1a = be1[c] - m * sc1a;
    m = stats[c + 1] * invM; vv = stats[129 + c] * invM - m * m;
    sc1b = g1[c + 1] * rsqrtf(vv + 1e-5f); sh1b = be1[c + 1] - m * sc1b;
    m = stats[256 + c] * invM; vv = stats[384 + c] * invM - m * m;
    sc2a = g2[c] * rsqrtf(vv + 1e-5f); sh2a = be2[c] - m * sc2a;
    m = stats[257 + c] * invM; vv = stats[385 + c] * invM - m * m;
    sc2b = g2[c + 1] * rsqrtf(vv + 1e-5f); sh2b = be2[c + 1] - m * sc2b;
  }
  u32 w1 = *(const u32*)(y1 + e0);
  u32 w2 = *(const u32*)(y2 + e0);
  float r0 = b2f((u16)w1) * sc1a + sh1a + b2f((u16)w2) * sc2a + sh2a;
  float r1 = b2f((u16)(w1 >> 16)) * sc1b + sh1b + b2f((u16)(w2 >> 16)) * sc2b + sh2b;
  *(u32*)(hout + e0) = (u32)f2b(r0) | ((u32)f2b(r1) << 16);
}

// out = bn3(y3): y3 tile layout, out row-major fp32
__global__ __launch_bounds__(256)
void norm_kernel(const u16* __restrict__ y3, const float* __restrict__ stats3,
                 const float* __restrict__ g3, const float* __restrict__ be3,
                 float* __restrict__ outp, float invM) {
  int i = blockIdx.x * 256 + threadIdx.x;
  int e0 = i * 2;
  int m = ((e0 >> 11) << 4) | ((e0 >> 5) & 15);
  int c = (((e0 >> 9) & 3) << 5) | (e0 & 31);
  float mm = stats3[c] * invM, vv = stats3[128 + c] * invM - mm * mm;
  float sca = g3[c] * rsqrtf(vv + 1e-5f), sha = be3[c] - mm * sca;
  mm = stats3[c + 1] * invM; vv = stats3[129 + c] * invM - mm * mm;
  float scb = g3[c + 1] * rsqrtf(vv + 1e-5f), shb = be3[c + 1] - mm * scb;
  u32 w = *(const u32*)(y3 + e0);
  float2 r;
  r.x = b2f((u16)w) * sca + sha;
  r.y = b2f((u16)(w >> 16)) * scb + shb;
  *(float2*)(outp + (size_t)m * 128 + c) = r;
}

// ---------------- launch ----------------
extern "C" void kernel_launch(void* const* d_in, const int* in_sizes, int n_in,
                              void* d_out, int out_size, void* d_ws, size_t ws_size,
                              hipStream_t stream) {
  const float* x   = (const float*)d_in[0];
  const int*   ei  = (const int*)d_in[1];
  const float* eps = (const float*)d_in[2];
  const float* Wl1 = (const float*)d_in[3];  const float* bl1 = (const float*)d_in[4];
  const float* Wl2 = (const float*)d_in[5];  const float* bl2 = (const float*)d_in[6];
  const float* g1  = (const float*)d_in[7];  const float* be1 = (const float*)d_in[8];
  const float* Wq  = (const float*)d_in[9];  const float* bq  = (const float*)d_in[10];
  const float* Wk  = (const float*)d_in[11]; const float* bk  = (const float*)d_in[12];
  const float* Wv  = (const float*)d_in[13]; const float* bv  = (const float*)d_in[14];
  const float* Wo  = (const float*)d_in[15]; const float* bo  = (const float*)d_in[16];
  const float* g2  = (const float*)d_in[17]; const float* be2 = (const float*)d_in[18];
  const float* Wf1 = (const float*)d_in[19]; const float* bf1 = (const float*)d_in[20];
  const float* Wf2 = (const float*)d_in[21]; const float* bf2 = (const float*)d_in[22];
  const float* g3  = (const float*)d_in[23]; const float* be3 = (const float*)d_in[24];
  float* out = (float*)d_out;

  const int N = in_sizes[0] / 128;   // 32768
  const int E = in_sizes[1] / 2;     // 524288
  const size_t MB = 1048576;
  const float invM = 1.0f / (float)N;

  char* ws = (char*)d_ws;
  u16* hin = (u16*)(ws + 0);          // [N,128] tile; agg out, later o_attn
  u16* t1  = (u16*)(ws + 8 * MB);     // [N,256] tile; later t2. CSR overlays pre-GEMM:
  int* deg    = (int*)(ws + 8 * MB);
  int* rowptr = (int*)(ws + 8 * MB + 256 * 1024);
  int* cursor = (int*)(ws + 8 * MB + 512 * 1024);
  int* csr    = (int*)(ws + 8 * MB + 768 * 1024);  // E ints = 2MB
  u16* qb  = (u16*)(ws + 24 * MB);    // q (head-major); later h_comb (tile)
  u16* kb  = (u16*)(ws + 32 * MB);    // k (head-major); later y3 (tile)
  u16* vb  = (u16*)(ws + 40 * MB);    // v (head-major)
  u16* xb  = (u16*)(ws + 48 * MB);    // bf16 x (tile); later y2 in-place
  u16* y2  = xb;
  float* stats = (float*)(ws + 56 * MB);         // s1,q1,s2,q2,s3,q3 (6*128)
  int* bsum = (int*)(ws + 56 * MB + 8192);
  int* boff = (int*)(ws + 56 * MB + 8192 + 512);
  u16* y1 = (u16*)d_out;              // d_out[0..8MB) as bf16 tile scratch
  u16*   BtAll   = (u16*)((char*)d_out + 8 * MB);                // 384 KB W^T tiles
  float* biasAll = (float*)((char*)d_out + 8 * MB + 400 * 1024); // 5 KB

  hipMemsetAsync(deg, 0, (size_t)N * sizeof(int), stream);
  hipMemsetAsync(stats, 0, 6 * 128 * sizeof(float), stream);

  const int* srcv = ei;
  const int* dstv = ei + E;
  const float QSCL = 0.25f * 1.44269504088896f;   // score scale * log2(e)

  prep_kernel<<<774, 256, 0, stream>>>(Wl1, Wl2, Wq, Wk, Wv, Wo, Wf1, Wf2,
                                       bl1, bl2, bq, bk, bv, bo, bf1, bf2,
                                       BtAll, biasAll);
  f2bf_kernel<<<(N * 128 / 2) / 256, 256, 0, stream>>>(x, xb);
  hist_kernel<<<(E + 255) / 256, 256, 0, stream>>>(dstv, deg, E);
  scan1_kernel<<<N / 256, 256, 0, stream>>>(deg, bsum);
  scan2_kernel<<<1, 128, 0, stream>>>(bsum, boff, rowptr + N);
  scan3_kernel<<<N / 256, 256, 0, stream>>>(deg, boff, rowptr, cursor);
  scatter_kernel<<<(E + 255) / 256, 256, 0, stream>>>(srcv, dstv, cursor, csr, E);
  agg_kernel<<<N / 4, 256, 0, stream>>>(xb, x, csr, rowptr, eps, hin, N);

  dim3 blk(256);
  // t1 = relu(hin @ Wl1 + bl1)          Nout=256 (ntshift=3)
  gemm_fast<128><<<dim3(N / 128, 8), blk, 0, stream>>>(hin, BtAll + 0, biasAll + 0,
      nullptr, t1, nullptr, nullptr, nullptr, nullptr, 3, 1, 1.0f, 0);
  // y1 = xb + t1 @ Wl2 + bl2  (+stats1)  Nout=128
  gemm_fast<256><<<dim3(N / 128, 4), blk, 0, stream>>>(t1, BtAll + 32768, biasAll + 256,
      xb, y1, nullptr, nullptr, stats + 0, stats + 128, 2, 0, 1.0f, 0);
  // q,k,v fused (3 tensors), HEAD-MAJOR outputs; q pre-scaled by QSCL
  gemm_fast<128><<<dim3(N / 128, 12), blk, 0, stream>>>(xb, BtAll + 65536, biasAll + 384,
      nullptr, qb, kb, vb, nullptr, nullptr, 2, 0, QSCL, 1);
  // attention -> o_attn (tile layout, reuse hin); grid = (b,h) x 2 q-halves
  attn_kernel<<<(N / 512) * 8 * 2, dim3(512), 0, stream>>>(qb, kb, vb, hin);
  // y2 = xb + o_attn @ Wo + bo  (+stats2)  (in-place over xb, same-thread RMW)
  gemm_fast<128><<<dim3(N / 128, 4), blk, 0, stream>>>(hin, BtAll + 114688, biasAll + 768,
      xb, y2, nullptr, nullptr, stats + 256, stats + 384, 2, 0, 1.0f, 0);
  // h = bn1(y1) + bn2(y2)  -> qb   (BN params inline)
  combine_kernel<<<(N * 128 / 2) / 256, blk, 0, stream>>>(y1, y2, stats,
      g1, be1, g2, be2, qb, invM);
  // t2 = relu(h @ Wf1 + bf1)            Nout=256
  gemm_fast<128><<<dim3(N / 128, 8), blk, 0, stream>>>(qb, BtAll + 131072, biasAll + 896,
      nullptr, t1, nullptr, nullptr, nullptr, nullptr, 3, 1, 1.0f, 0);
  // y3 = qb + t2 @ Wf2 + bf2  (+stats3)  -> kb
  gemm_fast<256><<<dim3(N / 128, 4), blk, 0, stream>>>(t1, BtAll + 163840, biasAll + 1152,
      qb, kb, nullptr, nullptr, stats + 512, stats + 640, 2, 0, 1.0f, 0);
  // out = bn3(y3)   (BN params inline)
  norm_kernel<<<(N * 128 / 2) / 256, blk, 0, stream>>>(kb, stats + 512, g3, be3, out, invM);
}